// Round 6
// baseline (201.029 us; speedup 1.0000x reference)
//
#include <hip/hip_runtime.h>

#define POOL 7
#define NCH 256
#define OUT_PER_BOX (NCH * POOL * POOL)   // 12544
#define PARTS 7
#define PART_SZ (OUT_PER_BOX / PARTS)     // 1792
#define ITERS (PART_SZ / 256)             // 7
#define PWORDS 64

// binned-path geometry
#define QGRID 4
#define NBIN_L (QGRID * QGRID)            // 16 bins per level
#define NLVL_BINNED 3                     // levels 3,4,5
#define NBINS (NBIN_L * NLVL_BINNED)      // 48
#define L2BIN NBINS                       // extra list slot for level-2 boxes
#define NLISTS (NBINS + 1)                // 49

#define C3 2                              // channels per block, level 3
#define C4 4
#define C5 4
#define NCHUNK3 (NCH / C3)                // 128
#define NCHUNK4 (NCH / C4)                // 64
#define NCHUNK5 (NCH / C5)                // 64
#define NBLK3 (NBIN_L * NCHUNK3)          // 2048
#define NBLK4 (NBIN_L * NCHUNK4)          // 1024
#define NBLK5 (NBIN_L * NCHUNK5)          // 1024
#define NBLK_BINNED (NBLK3 + NBLK4 + NBLK5) // 4096

#define REGION_FLOATS 12288               // 48 KB LDS region buffer

// params layout per box (ints; floats bit-cast), indexed by ORIGINAL box id:
//  [0..6] y0 (raw row)  [7..13] y1  [14..20] xb (pair base)  [21..27] xcl
//  [28..34] wy  [35..41] wx  [42..48] vy  [49..55] vx
//  [56] lvl-2  [57] H  [58] H*H  [59] box id
// meta per list (8 ints): [0]=cnt [1]=by0 [2]=by1 [3]=bx0 [4]=bx1(max col needed)

__global__ void init_kernel(int* __restrict__ meta) {
    const int i = threadIdx.x;
    if (i < NLISTS) {
        meta[i * 8 + 0] = 0;
        meta[i * 8 + 1] = 0x7fffffff;
        meta[i * 8 + 2] = -1;
        meta[i * 8 + 3] = 0x7fffffff;
        meta[i * 8 + 4] = -1;
    }
}

// ---------------------------------------------------------------------------
// Prep: one WAVE per box; lane j computes params word j -> fully coalesced
// param stores. Lane 0 does the list atomics (count, append, bbox union).
// ---------------------------------------------------------------------------
__global__ __launch_bounds__(256) void prep_kernel(
    const float* __restrict__ boxes, int* __restrict__ params,
    int* __restrict__ meta, int* __restrict__ lists, int nbox)
{
    const int n = blockIdx.x * 4 + (threadIdx.x >> 6);
    const int j = threadIdx.x & 63;
    if (n >= nbox) return;

    const float by1 = boxes[n * 4 + 0];
    const float bx1 = boxes[n * 4 + 1];
    const float by2 = boxes[n * 4 + 2];
    const float bx2 = boxes[n * 4 + 3];
    const float h = by2 - by1;
    const float w = bx2 - bx1;
    const float lvlf = 4.0f + log2f(sqrtf(h * w) / 0.21875f);
    int lvl = (int)rintf(lvlf);               // round-half-even = jnp.round
    lvl = lvl < 2 ? 2 : (lvl > 5 ? 5 : lvl);
    const int H = 256 >> (lvl - 2);
    const float Hm1 = (float)(H - 1);

    const int t = j % 7;                       // meaningful for j<56
    const float tt = (float)t * (1.0f / 6.0f);

    const float yy  = (by1 + h * tt) * Hm1;
    const float y0f = floorf(yy);
    int y0 = (int)y0f; y0 = min(H - 1, max(0, y0));
    const int y1c = min(H - 1, y0 + 1);

    const float xx  = (bx1 + w * tt) * Hm1;
    const float x0f = floorf(xx);
    int x0 = (int)x0f; x0 = min(H - 1, max(0, x0));
    const int xb  = min(x0, H - 2);
    const int xcl = (x0 == H - 1) ? 1 : 0;

    int val;
    switch (j / 7) {
        case 0: val = y0;   break;
        case 1: val = y1c;  break;
        case 2: val = xb;   break;
        case 3: val = xcl;  break;
        case 4: val = __float_as_int(yy - y0f); break;     // wy (unclipped floor)
        case 5: val = __float_as_int(xx - x0f); break;     // wx
        case 6: val = __float_as_int((yy >= 0.0f && yy <= Hm1) ? 1.0f : 0.0f); break;
        case 7: val = __float_as_int((xx >= 0.0f && xx <= Hm1) ? 1.0f : 0.0f); break;
        default: {
            const int r = j - 56;
            val = (r == 0) ? (lvl - 2) : (r == 1) ? H : (r == 2) ? H * H
                : (r == 3) ? n : 0;
        }
    }
    params[n * PWORDS + j] = val;

    if (j == 0) {
        if (lvl == 2) {
            const int slot = atomicAdd(&meta[L2BIN * 8 + 0], 1);
            lists[L2BIN * nbox + slot] = n;
        } else {
            const float cy = 0.5f * (by1 + by2);
            const float cx = 0.5f * (bx1 + bx2);
            int qy = (int)(cy * 4.0f); qy = qy < 0 ? 0 : (qy > 3 ? 3 : qy);
            int qx = (int)(cx * 4.0f); qx = qx < 0 ? 0 : (qx > 3 ? 3 : qx);
            const int bin = (lvl - 3) * NBIN_L + qy * QGRID + qx;
            const int slot = atomicAdd(&meta[bin * 8 + 0], 1);
            lists[bin * nbox + slot] = n;
            // extremes: t=0 gives min y0/xb; t=6 gives max (yy,xx monotonic, h,w>0)
            const float yy6 = (by1 + h) * Hm1;
            int y06 = (int)floorf(yy6); y06 = min(H - 1, max(0, y06));
            const int y16 = min(H - 1, y06 + 1);
            const float xx6 = (bx1 + w) * Hm1;
            int x06 = (int)floorf(xx6); x06 = min(H - 1, max(0, x06));
            const int xb6 = min(x06, H - 2);
            atomicMin(&meta[bin * 8 + 1], y0);
            atomicMax(&meta[bin * 8 + 2], y16);
            atomicMin(&meta[bin * 8 + 3], xb);
            atomicMax(&meta[bin * 8 + 4], xb6 + 1);
        }
    }
}

// ---------------------------------------------------------------------------
// Unified main kernel.
//  blocks [0, NBLK_BINNED): binned path (levels 3-5) — stage bin-region into
//    LDS once with float4 loads, sample all bin boxes from LDS.
//  blocks [NBLK_BINNED, +nbox*7): level-2 gather path (verified R0 body,
//    params precomputed, boxes via indirect list; surplus blocks exit after
//    one scalar load).
// ---------------------------------------------------------------------------
__global__ __launch_bounds__(256) void main_kernel(
    const float* __restrict__ p2,
    const float* __restrict__ p3,
    const float* __restrict__ p4,
    const float* __restrict__ p5,
    float* __restrict__ out,
    const int* __restrict__ params,
    const int* __restrict__ meta,
    const int* __restrict__ lists,
    int nbox)
{
    __shared__ float region[REGION_FLOATS];
    __shared__ int sPm[2 * PWORDS];

    const int bid = blockIdx.x;
    const int tid = threadIdx.x;

    if (bid >= NBLK_BINNED) {
        // ---------------- level-2 gather path (R0 body) ----------------
        const int bid2 = bid - NBLK_BINNED;
        const int rank = bid2 / PARTS;
        const int part = bid2 - rank * PARTS;
        if (rank >= meta[L2BIN * 8 + 0]) return;   // cheap exit for surplus blocks
        const int n = lists[L2BIN * nbox + rank];
        if (tid < PWORDS) sPm[tid] = params[n * PWORDS + tid];
        __syncthreads();
        const float* fm = p2;
        const int H = 256, HW = 65536;

        const size_t out_base = (size_t)n * OUT_PER_BOX + (size_t)part * PART_SZ;
        const int idx0 = part * PART_SZ + tid;

        float2 q0[ITERS], q1[ITERS];
        #pragma unroll
        for (int i = 0; i < ITERS; ++i) {
            const int idx = idx0 + i * 256;
            const int c  = idx / 49;
            const int r  = idx - c * 49;
            const int py = r / 7;
            const int px = r - py * 7;
            const float* fmc = fm + (size_t)c * HW;
            const int xb = sPm[14 + px];
            q0[i] = *(const float2*)(fmc + sPm[py] * H + xb);
            q1[i] = *(const float2*)(fmc + sPm[7 + py] * H + xb);
        }
        #pragma unroll
        for (int i = 0; i < ITERS; ++i) {
            const int idx = idx0 + i * 256;
            const int c  = idx / 49;
            const int r  = idx - c * 49;
            const int py = r / 7;
            const int px = r - py * 7;
            const float wy = __int_as_float(sPm[28 + py]);
            const float wx = __int_as_float(sPm[35 + px]);
            const int   cl = sPm[21 + px];
            const float v00 = cl ? q0[i].y : q0[i].x;
            const float v01 = q0[i].y;
            const float v10 = cl ? q1[i].y : q1[i].x;
            const float v11 = q1[i].y;
            const float r0 = v00 + wx * (v01 - v00);
            const float r1 = v10 + wx * (v11 - v10);
            out[out_base + (size_t)(i * 256 + tid)] =
                (r0 + wy * (r1 - r0)) * __int_as_float(sPm[42 + py])
                                      * __int_as_float(sPm[49 + px]);
        }
        return;
    }

    // ---------------- binned path (levels 3-5) ----------------
    int b = bid;
    int lvlm, bin, c0, C, BPP;
    if (b < NBLK3)              { lvlm = 0; bin = b / NCHUNK3; c0 = (b % NCHUNK3) * C3; C = C3; BPP = 2; }
    else if (b < NBLK3 + NBLK4) { b -= NBLK3; lvlm = 1; bin = b / NCHUNK4; c0 = (b % NCHUNK4) * C4; C = C4; BPP = 1; }
    else                        { b -= NBLK3 + NBLK4; lvlm = 2; bin = b / NCHUNK5; c0 = (b % NCHUNK5) * C5; C = C5; BPP = 1; }

    const int gbin = lvlm * NBIN_L + bin;
    const int cnt  = meta[gbin * 8 + 0];
    if (cnt == 0) return;

    const int H  = 128 >> lvlm;               // 128 / 64 / 32
    const int HW = H * H;
    const float* fm = (lvlm == 0) ? p3 : (lvlm == 1) ? p4 : p5;

    const int by0 = meta[gbin * 8 + 1];
    const int by1 = meta[gbin * 8 + 2];
    const int bx0 = meta[gbin * 8 + 3] & ~3;  // align down to float4
    const int bx1 = meta[gbin * 8 + 4];       // max col needed (xb+1)
    const int R   = by1 - by0 + 1;
    const int n4  = (bx1 - bx0 + 4) >> 2;     // float4 chunks per row
    const int W   = n4 * 4;                   // LDS row pitch
    const bool use_lds = (C * R * W) <= REGION_FLOATS;

    if (use_lds) {
        // stage region: per channel, rows [by0,by1], cols [bx0, bx0+W).
        // chunk starts are mult-of-4 and <= bx1 <= H-1 -> <= H-4: never OOB.
        const int RW4 = R * n4;
        const int tot = C * RW4;
        for (int q = tid; q < tot; q += 256) {
            const int c    = q / RW4;
            const int rem2 = q - c * RW4;
            const int r    = rem2 / n4;
            const int w4   = rem2 - r * n4;
            const float4 v = *(const float4*)(fm + (size_t)(c0 + c) * HW
                                              + (by0 + r) * H + bx0 + w4 * 4);
            *(float4*)&region[(c * R + r) * W + w4 * 4] = v;
        }
    }

    // per-thread sampling coordinates (constant over the box loop)
    const int npb  = C * 49;                  // 98 or 196
    const int act  = BPP * npb;               // 196
    const int bsel = tid / npb;
    const int rem  = tid - bsel * npb;
    const int cl   = rem / 49;
    const int pos  = rem - cl * 49;
    const int py   = pos / 7;
    const int px   = pos - py * 7;
    const int obase = (c0 + cl) * 49 + pos;

    for (int k = 0; k < cnt; k += BPP) {
        __syncthreads();                      // protect sPm (and region, 1st iter)
        if (tid < BPP * PWORDS) {
            const int bb = tid >> 6;
            const int kk2 = k + bb;
            if (kk2 < cnt)
                sPm[tid] = params[lists[gbin * nbox + kk2] * PWORDS + (tid & 63)];
        }
        __syncthreads();
        const int kk = k + bsel;
        if (tid < act && kk < cnt) {
            const int* P = sPm + bsel * PWORDS;
            const int r0 = P[py]     - by0;
            const int r1 = P[7 + py] - by0;
            const int xo = P[14 + px] - bx0;
            const int clx = P[21 + px];
            float v00, v01, v10, v11;
            if (use_lds) {
                const float* base = &region[cl * R * W];
                v00 = base[r0 * W + xo + clx];
                v01 = base[r0 * W + xo + 1];
                v10 = base[r1 * W + xo + clx];
                v11 = base[r1 * W + xo + 1];
            } else {
                const float* basep = fm + (size_t)(c0 + cl) * HW;
                const int xa = P[14 + px];
                v00 = basep[P[py] * H + xa + clx];
                v01 = basep[P[py] * H + xa + 1];
                v10 = basep[P[7 + py] * H + xa + clx];
                v11 = basep[P[7 + py] * H + xa + 1];
            }
            const float wy = __int_as_float(P[28 + py]);
            const float wx = __int_as_float(P[35 + px]);
            const float a0 = v00 + wx * (v01 - v00);
            const float a1 = v10 + wx * (v11 - v10);
            const float val = (a0 + wy * (a1 - a0))
                              * __int_as_float(P[42 + py])
                              * __int_as_float(P[49 + px]);
            out[(size_t)P[59] * OUT_PER_BOX + obase] = val;
        }
    }
}

// ---------------------------------------------------------------------------
// Safety fallback (workspace too small): verified round-0 flat kernel.
// ---------------------------------------------------------------------------
__global__ __launch_bounds__(256) void roi_align_flat_kernel(
    const float* __restrict__ boxes,
    const float* __restrict__ p2, const float* __restrict__ p3,
    const float* __restrict__ p4, const float* __restrict__ p5,
    float* __restrict__ out, int nbox)
{
    const int n    = blockIdx.x % nbox;
    const int part = blockIdx.x / nbox;
    const int tid  = threadIdx.x;

    __shared__ int   s_y0[POOL], s_y1[POOL], s_xb[POOL], s_xcl[POOL];
    __shared__ float s_wy[POOL], s_wx[POOL], s_vy[POOL], s_vx[POOL];

    const float by1 = boxes[n * 4 + 0];
    const float bx1 = boxes[n * 4 + 1];
    const float by2 = boxes[n * 4 + 2];
    const float bx2 = boxes[n * 4 + 3];
    const float h = by2 - by1;
    const float w = bx2 - bx1;
    const float lvlf = 4.0f + log2f(sqrtf(h * w) / 0.21875f);
    int lvl = (int)rintf(lvlf);
    lvl = lvl < 2 ? 2 : (lvl > 5 ? 5 : lvl);

    const float* fm;
    int H;
    switch (lvl) {
        case 2:  fm = p2; H = 256; break;
        case 3:  fm = p3; H = 128; break;
        case 4:  fm = p4; H = 64;  break;
        default: fm = p5; H = 32;  break;
    }
    const float Hm1 = (float)(H - 1);

    if (tid < POOL) {
        const float t = (float)tid * (1.0f / 6.0f);
        const float yy  = (by1 + h * t) * Hm1;
        const float y0f = floorf(yy);
        int y0 = (int)y0f;
        y0 = min(H - 1, max(0, y0));
        s_y0[tid] = y0;
        s_y1[tid] = min(H - 1, y0 + 1);
        s_wy[tid] = yy - y0f;
        s_vy[tid] = (yy >= 0.0f && yy <= Hm1) ? 1.0f : 0.0f;
        const float xx  = (bx1 + w * t) * Hm1;
        const float x0f = floorf(xx);
        int x0 = (int)x0f;
        x0 = min(H - 1, max(0, x0));
        s_xb[tid]  = min(x0, H - 2);
        s_xcl[tid] = (x0 == H - 1) ? 1 : 0;
        s_wx[tid]  = xx - x0f;
        s_vx[tid]  = (xx >= 0.0f && xx <= Hm1) ? 1.0f : 0.0f;
    }
    __syncthreads();

    const size_t out_base = (size_t)n * OUT_PER_BOX + (size_t)part * PART_SZ;
    const int idx0 = part * PART_SZ + tid;
    const int HW = H * H;

    float2 q0[ITERS], q1[ITERS];
    #pragma unroll
    for (int i = 0; i < ITERS; ++i) {
        const int idx = idx0 + i * 256;
        const int c  = idx / 49;
        const int r  = idx - c * 49;
        const int py = r / 7;
        const int px = r - py * 7;
        const float* fmc = fm + (size_t)c * HW;
        const int xb = s_xb[px];
        q0[i] = *(const float2*)(fmc + s_y0[py] * H + xb);
        q1[i] = *(const float2*)(fmc + s_y1[py] * H + xb);
    }
    #pragma unroll
    for (int i = 0; i < ITERS; ++i) {
        const int idx = idx0 + i * 256;
        const int c  = idx / 49;
        const int r  = idx - c * 49;
        const int py = r / 7;
        const int px = r - py * 7;
        const float wy = s_wy[py], wx = s_wx[px];
        const int   cl = s_xcl[px];
        const float v00 = cl ? q0[i].y : q0[i].x;
        const float v01 = q0[i].y;
        const float v10 = cl ? q1[i].y : q1[i].x;
        const float v11 = q1[i].y;
        const float r0 = v00 + wx * (v01 - v00);
        const float r1 = v10 + wx * (v11 - v10);
        out[out_base + (size_t)(i * 256 + tid)] =
            (r0 + wy * (r1 - r0)) * s_vy[py] * s_vx[px];
    }
}

extern "C" void kernel_launch(void* const* d_in, const int* in_sizes, int n_in,
                              void* d_out, int out_size, void* d_ws, size_t ws_size,
                              hipStream_t stream) {
    const float* boxes = (const float*)d_in[0];
    const float* p2    = (const float*)d_in[1];
    const float* p3    = (const float*)d_in[2];
    const float* p4    = (const float*)d_in[3];
    const float* p5    = (const float*)d_in[4];
    float* out         = (float*)d_out;

    const int nbox = in_sizes[0] / 4;   // 1000
    const size_t params_b = (size_t)nbox * PWORDS * sizeof(int);
    const size_t meta_b   = (size_t)NLISTS * 8 * sizeof(int);
    const size_t lists_b  = (size_t)NLISTS * nbox * sizeof(int);
    const size_t need     = params_b + meta_b + lists_b;   // ~455 KB @ nbox=1000

    if (ws_size < need) {
        roi_align_flat_kernel<<<nbox * PARTS, 256, 0, stream>>>(
            boxes, p2, p3, p4, p5, out, nbox);
        return;
    }

    int* params = (int*)d_ws;
    int* meta   = (int*)((char*)d_ws + params_b);
    int* lists  = (int*)((char*)d_ws + params_b + meta_b);

    init_kernel<<<1, 64, 0, stream>>>(meta);
    prep_kernel<<<(nbox + 3) / 4, 256, 0, stream>>>(boxes, params, meta, lists, nbox);
    main_kernel<<<NBLK_BINNED + nbox * PARTS, 256, 0, stream>>>(
        p2, p3, p4, p5, out, params, meta, lists, nbox);
}